// Round 10
// baseline (216.294 us; speedup 1.0000x reference)
//
#include <hip/hip_runtime.h>
#include <cstdint>

#define BB 8
#define CC 128
#define HH 96
#define WW 160
#define HWsz (HH * WW)                 // 15360
#define TH 8
#define TW 32
#define CSTEP 8
#define HALO_H 16                      // TH + 8
#define SW2 64                         // x2 row stride in words, POWER OF 2 (R9 bank algebra)
#define CI_WORDS (HALO_H * SW2)        // 1024 words = 4 KB per channel slice
#define X2W (CSTEP * CI_WORDS)         // 8192 words = 32 KB per x2 buffer
#define X2_SLOTS (X2W / 64)            // 128 row-slots per chunk
#define NSTG2 15                       // x2 stage loads per wave (uniform, redirect scheme)
#define NWAVES 9
#define NTHREADS (NWAVES * 64)         // 576
#define NCHUNKS (CC / CSTEP)           // 16
#define NBLOCKS (BB * (HH / TH) * (WW / TW))  // 480

__device__ __forceinline__ void g2l_dword(const float* g, float* l) {
  __builtin_amdgcn_global_load_lds((const __attribute__((address_space(1))) void*)g,
                                   (__attribute__((address_space(3))) void*)l,
                                   4, 0, 0);
}

// R10 = R9's swizzled-x2 schedule MINUS the x1 LDS path (x1 = direct per-lane
// global float4 inside compute, R0-proven). Rationale (9-round reconciliation):
// the wall is DS-pipe-bound at ~60-70% busy WHEN 2 blocks/CU are resident;
// this round cuts DS instructions 25% (32->24 per chunk-wave) and keeps R9's
// conflict reduction, at LDS 64 KB (2 blocks/CU with 32 KB margin — R9's
// 80 KB exact-fit likely dropped to 1 block/CU and forfeited its gain).
// vmcnt bookkeeping: stage = 15 g2l/wave. At [B](k) the FIFO holds
// [x1(k-1) stragglers <=8][stage(k+1) 15]; vmcnt(15) keeps exactly stage(k+1)
// and formally drains stage(k) (older). The compiler's own a4-waits inside
// compute(k-1) already drained stage(k) early — harmless (R0 empirics).
extern "C" __global__ void __launch_bounds__(NTHREADS, 2)
corr81_kernel(const float* __restrict__ x1, const float* __restrict__ x2,
              float* __restrict__ out)
{
  __shared__ __align__(16) float lds[2 * X2W];   // 64 KB -> 2 blocks/CU safe

  const int tid  = threadIdx.x;
  const int wv   = tid >> 6;                              // dy 0..8 (wave-uniform)
  const int wvu  = __builtin_amdgcn_readfirstlane(wv);
  const int lane = tid & 63;
  const int r    = lane >> 3;    // tile row 0..7
  const int j    = lane & 7;     // w-slot 0..7 (4 px each)

  // XCD-bijective swizzle (validated: FETCH 184 -> 65 MB).
  const int bid0 = blockIdx.x;
  const int bid  = (bid0 & 7) * (NBLOCKS / 8) + (bid0 >> 3);

  const int wt = bid % (WW / TW);
  const int ht = (bid / (WW / TW)) % (HH / TH);
  const int b  = bid / ((WW / TW) * (HH / TH));
  const int h0 = ht * TH;
  const int w0 = wt * TW;

  // ---- per-lane staged-column VGPRs (R9 verbatim): slot i uses group i&3,
  // m = (wvu+i)&3 since 9i = i mod 4. Clamp folds replicate-pad.
  int gw[4];
#pragma unroll
  for (int g = 0; g < 4; ++g) {
    const int m  = (wvu + g) & 3;
    const int cl = lane ^ (m << 2);              // logical col this lane stages
    int gwv = w0 + cl - 4;
    gwv = gwv < 0 ? 0 : (gwv > WW - 1 ? WW - 1 : gwv);
    gw[g] = gwv;
  }
  // slot 14 redirect: idx = wvu+126 >= 128 for wvu >= 2 -> own slot 0 (same
  // src+dst bytes, benign WAW; R9-proven).
  const int gw14v = (wvu + 9 * 14 < X2_SLOTS) ? gw[14 & 3] : gw[0];

  // ---- wave-uniform scalar parts of staging addresses (SGPRs), R9 verbatim.
  int sb2[NSTG2]; uint32_t doff2[NSTG2];
#pragma unroll
  for (int i = 0; i < NSTG2; ++i) {
    int idx = wvu + 9 * i;
    if (idx >= X2_SLOTS) idx = wvu;              // redirect to own slot 0
    const int ci  = idx >> 4;
    const int row = idx & 15;
    int gh = h0 + row - 4; gh = gh < 0 ? 0 : (gh > HH - 1 ? HH - 1 : gh);
    sb2[i]  = (ci * HH + gh) * WW;
    doff2[i] = (uint32_t)(idx * 64);
  }

  const float* x2b = x2 + (size_t)b * CC * HWsz;
  // x1: direct per-lane pointer (R0-proven path; 9 waves share the same tile
  // -> L1/L2 broadcast hits, no LDS, no staging).
  const float* x1p = x1 + (size_t)b * CC * HWsz + (size_t)(h0 + r) * WW + (w0 + 4 * j);

  float acc[9][4];
#pragma unroll
  for (int d = 0; d < 9; ++d)
#pragma unroll
    for (int p = 0; p < 4; ++p) acc[d][p] = 0.f;

  // x2 read bases (R9 verbatim): phys word = R*64 + 4*((j+t)^m), m = R&3.
  const int R = r + wv;
  const int m = R & 3;
  const int B0 = R * SW2 + (((j + 0) ^ m) << 2);
  const int B1 = R * SW2 + (((j + 1) ^ m) << 2);
  const int B2 = R * SW2 + (((j + 2) ^ m) << 2);

  // ---- prologue: stage chunk 0 (15 loads)
#pragma unroll
  for (int i = 0; i < NSTG2 - 1; ++i)
    g2l_dword(x2b + sb2[i] + gw[i & 3], &lds[doff2[i]]);
  g2l_dword(x2b + sb2[14] + gw14v, &lds[doff2[14]]);

#pragma unroll 1
  for (int k = 0; k < NCHUNKS - 1; ++k) {
    // [A] issue stage(k+1): 15 x2 loads, precomputed offsets
    {
      const float* s2 = x2b + (size_t)(k + 1) * (CSTEP * HWsz);
      float* d2 = &lds[((k + 1) & 1) * X2W];
#pragma unroll
      for (int i = 0; i < NSTG2 - 1; ++i)
        g2l_dword(s2 + sb2[i] + gw[i & 3], d2 + doff2[i]);
      g2l_dword(s2 + sb2[14] + gw14v, d2 + doff2[14]);
    }

    // [B] counted wait: keeps stage(k+1)'s 15 in flight; guarantees stage(k)
    // (and any x1 stragglers) drained.
    __builtin_amdgcn_sched_barrier(0);
    asm volatile("s_waitcnt vmcnt(15)" ::: "memory");
    __builtin_amdgcn_sched_barrier(0);
    __builtin_amdgcn_s_barrier();
    __builtin_amdgcn_sched_barrier(0);

    // [D] compute chunk k: 24 ds_read_b128 + 8 direct x1 float4 + 288 FMA
    {
      const float* xb = &lds[(k & 1) * X2W];
      const float* xc = x1p + (size_t)k * (CSTEP * HWsz);
#pragma unroll
      for (int ci = 0; ci < CSTEP; ++ci) {
        const float4 a4 = *(const float4*)(xc + (size_t)ci * HWsz);
        const float4 f0 = *(const float4*)(xb + B0 + ci * CI_WORDS);
        const float4 f1 = *(const float4*)(xb + B1 + ci * CI_WORDS);
        const float4 f2 = *(const float4*)(xb + B2 + ci * CI_WORDS);
        const float av[4] = {a4.x, a4.y, a4.z, a4.w};
        const float w12[12] = {f0.x, f0.y, f0.z, f0.w,
                               f1.x, f1.y, f1.z, f1.w,
                               f2.x, f2.y, f2.z, f2.w};
#pragma unroll
        for (int d = 0; d < 9; ++d)
#pragma unroll
          for (int p = 0; p < 4; ++p)
            acc[d][p] = fmaf(av[p], w12[d + p], acc[d][p]);
      }
    }

    // [C2] WAR barrier
    __builtin_amdgcn_sched_barrier(0);
    __builtin_amdgcn_s_barrier();
    __builtin_amdgcn_sched_barrier(0);
  }

  // ---- peeled last chunk (k = 15, buf 1): nothing left to prefetch
  asm volatile("s_waitcnt vmcnt(0)" ::: "memory");
  __builtin_amdgcn_sched_barrier(0);
  __builtin_amdgcn_s_barrier();
  __builtin_amdgcn_sched_barrier(0);
  {
    const int k = NCHUNKS - 1;
    const float* xb = &lds[(k & 1) * X2W];
    const float* xc = x1p + (size_t)k * (CSTEP * HWsz);
#pragma unroll
    for (int ci = 0; ci < CSTEP; ++ci) {
      const float4 a4 = *(const float4*)(xc + (size_t)ci * HWsz);
      const float4 f0 = *(const float4*)(xb + B0 + ci * CI_WORDS);
      const float4 f1 = *(const float4*)(xb + B1 + ci * CI_WORDS);
      const float4 f2 = *(const float4*)(xb + B2 + ci * CI_WORDS);
      const float av[4] = {a4.x, a4.y, a4.z, a4.w};
      const float w12[12] = {f0.x, f0.y, f0.z, f0.w,
                             f1.x, f1.y, f1.z, f1.w,
                             f2.x, f2.y, f2.z, f2.w};
#pragma unroll
      for (int d = 0; d < 9; ++d)
#pragma unroll
        for (int p = 0; p < 4; ++p)
          acc[d][p] = fmaf(av[p], w12[d + p], acc[d][p]);
    }
  }

  // ---- epilogue (R0/R3 verbatim): out[((b*81 + wv*9+d)*H + h0+r)*W + w0+4j], /8
  float* op = out + (((size_t)b * 81 + (size_t)wv * 9) * HH + (h0 + r)) * WW + (w0 + 4 * j);
#pragma unroll
  for (int d = 0; d < 9; ++d) {
    float4 v;
    v.x = acc[d][0] * 0.125f;
    v.y = acc[d][1] * 0.125f;
    v.z = acc[d][2] * 0.125f;
    v.w = acc[d][3] * 0.125f;
    *(float4*)(op + (size_t)d * HWsz) = v;
  }
}

extern "C" void kernel_launch(void* const* d_in, const int* in_sizes, int n_in,
                              void* d_out, int out_size, void* d_ws, size_t ws_size,
                              hipStream_t stream) {
  const float* x1 = (const float*)d_in[0];
  const float* x2 = (const float*)d_in[1];
  float* out = (float*)d_out;
  corr81_kernel<<<dim3(NBLOCKS), dim3(NTHREADS), 0, stream>>>(x1, x2, out);
}